// Round 1
// 432.700 us; speedup vs baseline: 1.0214x; 1.0214x over previous
//
#include <hip/hip_runtime.h>
#include <cstdint>
#include <cstddef>

#define B_   8
#define LQ_  2048
#define LK_  2048

typedef __attribute__((ext_vector_type(8))) __bf16 bf16x8;
typedef __attribute__((ext_vector_type(4))) float f32x4;
typedef __attribute__((ext_vector_type(8))) unsigned short ushortx8;

__device__ __forceinline__ unsigned short f2bf(float f) {
  unsigned u = __builtin_bit_cast(unsigned, f);
  u = u + 0x7fffu + ((u >> 16) & 1u);  // round-to-nearest-even
  return (unsigned short)(u >> 16);
}
__device__ __forceinline__ float bf2f(unsigned short h) {
  unsigned u = ((unsigned)h) << 16;
  return __builtin_bit_cast(float, u);
}

__device__ __forceinline__ void gld_lds16(const void* g, void* l) {
  __builtin_amdgcn_global_load_lds((__attribute__((address_space(1))) void*)(void*)g,
                                   (__attribute__((address_space(3))) void*)l, 16, 0, 0);
}

// ------------- flat cast fp32 -> bf16 for queries+keys in one launch -------------
__global__ __launch_bounds__(256) void cast2_bf16_kernel(
    const float* __restrict__ in0, unsigned short* __restrict__ out0,
    const float* __restrict__ in1, unsigned short* __restrict__ out1,
    size_t half_blocks) {
  const float* in = blockIdx.x < half_blocks ? in0 : in1;
  unsigned short* out = blockIdx.x < half_blocks ? out0 : out1;
  size_t bb = blockIdx.x < half_blocks ? blockIdx.x : blockIdx.x - half_blocks;
  size_t i = (bb * 256 + threadIdx.x) * 8;
  float4 a = *(const float4*)(in + i);
  float4 b = *(const float4*)(in + i + 4);
  ushortx8 o;
  o[0] = f2bf(a.x); o[1] = f2bf(a.y); o[2] = f2bf(a.z); o[3] = f2bf(a.w);
  o[4] = f2bf(b.x); o[5] = f2bf(b.y); o[6] = f2bf(b.z); o[7] = f2bf(b.w);
  *(ushortx8*)(out + i) = o;
}

// ---------------- transpose + cast: fp32 [R][C] -> bf16 [C][R] ----------------
__global__ __launch_bounds__(256) void transpose_cast_kernel(
    const float* __restrict__ in, unsigned short* __restrict__ out,
    int R, int C, long in_bstride, long out_bstride) {
  __shared__ float t[32][33];
  const float* inb = in + (size_t)blockIdx.z * in_bstride;
  unsigned short* outb = out + (size_t)blockIdx.z * out_bstride;
  int c0 = blockIdx.x * 32, r0 = blockIdx.y * 32;
  int tx = threadIdx.x, ty = threadIdx.y;  // block (32,8)
#pragma unroll
  for (int k = 0; k < 4; ++k) {
    int r = ty + k * 8;
    t[r][tx] = inb[(size_t)(r0 + r) * C + c0 + tx];
  }
  __syncthreads();
#pragma unroll
  for (int k = 0; k < 4; ++k) {
    int c = ty + k * 8;
    outb[(size_t)(c0 + c) * R + r0 + tx] = f2bf(t[tx][c]);
  }
}

// ---------------- GEMM: C[M,N] = A[M,K] @ Bt[N,K]^T, BK=64, double-buffered ----------------
// Grid: (x = N-tile, y = M-tile, z = batch). n-tile rotated by batch so each
// batch spreads over all XCDs (valid_len skipping would otherwise imbalance).
// LDS tiles 128x64 bf16 x 2 slots (64 KiB), XOR-swizzled at 16B chunks;
// global_load_lds dst is forced base+lane*16, so swizzle inverts the global
// source address.
// K-loop: issue stage(t+1 -> slot^1), compute(t from slot), ONE barrier.
// Race-free: slot^1's old contents (tile t-1) were fully read before the
// barrier that ended the previous iteration, so stagings only target dead LDS.
// OUTM: 0 = bf16, 1 = bf16 scaled, 2 = fp32
// SKIPN: early-exit blocks with n0 >= valid_len (output overwritten by softmax)
// CLAMPK: clamp K-loop to round_up(valid_len,64) (A cols beyond are exact 0)
template <int OUTM, int SKIPN, int CLAMPK>
__global__ __launch_bounds__(256) void gemm_bt_kernel(
    const unsigned short* __restrict__ A, const unsigned short* __restrict__ B,
    void* __restrict__ Cp, int M, int N, int K,
    long a_bstride, long b_bstride, long c_bstride, float scale,
    const int* __restrict__ vlp) {
  __shared__ unsigned short lA[2][128 * 64];
  __shared__ unsigned short lB[2][128 * 64];

  const int tid = threadIdx.x;
  const int wave = tid >> 6;
  const int lane = tid & 63;
  const int lane15 = lane & 15;
  const int lhalf = lane >> 4;
  const int nt = (int)((blockIdx.x + 2 * blockIdx.z) & (gridDim.x - 1));
  const int m0 = blockIdx.y * 128;
  const int n0 = nt * 128;

  int vl = K;
  if constexpr (SKIPN || CLAMPK) vl = vlp[blockIdx.z];
  if constexpr (SKIPN) {
    if (n0 >= vl) return;
  }
  int kEnd = K;
  if constexpr (CLAMPK) {
    int ke = (vl + 63) & ~63;
    kEnd = ke < K ? ke : K;
  }

  const int wm = (wave & 1) * 64;
  const int wn = (wave >> 1) * 64;

  const unsigned short* Ab = A + (size_t)blockIdx.z * a_bstride;
  const unsigned short* Bb = B + (size_t)blockIdx.z * b_bstride;

  // staging: 1024 16B-chunks per 128x64 tile, 4 per thread per operand.
  int sr[4], sc[4], sb[4];
#pragma unroll
  for (int j = 0; j < 4; ++j) {
    int blk = (wave * 4 + j) * 64 + lane;
    sb[j] = blk;
    sr[j] = blk >> 3;
    sc[j] = ((blk & 7) ^ ((blk >> 3) & 7)) * 8;
  }

  f32x4 acc[4][4];
#pragma unroll
  for (int i = 0; i < 4; ++i)
#pragma unroll
    for (int j = 0; j < 4; ++j)
      acc[i][j] = (f32x4){0.f, 0.f, 0.f, 0.f};

  const int rswz = lane15 & 7;

  // ---- prologue: stage K-tile 0 into slot 0 ----
#pragma unroll
  for (int j = 0; j < 4; ++j)
    gld_lds16(Ab + (size_t)(m0 + sr[j]) * K + sc[j], &lA[0][sb[j] * 8]);
#pragma unroll
  for (int j = 0; j < 4; ++j)
    gld_lds16(Bb + (size_t)(n0 + sr[j]) * K + sc[j], &lB[0][sb[j] * 8]);
  __syncthreads();  // drains vmcnt(0): tile 0 resident

  int slot = 0;
  for (int k0 = 0; k0 < kEnd; k0 += 64) {
    // issue next tile's staging first — lands under this tile's MFMAs
    if (k0 + 64 < kEnd) {
#pragma unroll
      for (int j = 0; j < 4; ++j)
        gld_lds16(Ab + (size_t)(m0 + sr[j]) * K + (k0 + 64 + sc[j]),
                  &lA[slot ^ 1][sb[j] * 8]);
#pragma unroll
      for (int j = 0; j < 4; ++j)
        gld_lds16(Bb + (size_t)(n0 + sr[j]) * K + (k0 + 64 + sc[j]),
                  &lB[slot ^ 1][sb[j] * 8]);
    }

#pragma unroll
    for (int s = 0; s < 2; ++s) {
      const int cA = ((s * 4 + lhalf) ^ rswz) * 8;
      bf16x8 af[4], bfr[4];
#pragma unroll
      for (int i = 0; i < 4; ++i)
        af[i] = *(const bf16x8*)&lA[slot][(wm + i * 16 + lane15) * 64 + cA];
#pragma unroll
      for (int j = 0; j < 4; ++j)
        bfr[j] = *(const bf16x8*)&lB[slot][(wn + j * 16 + lane15) * 64 + cA];
#pragma unroll
      for (int i = 0; i < 4; ++i)
#pragma unroll
        for (int j = 0; j < 4; ++j)
          acc[i][j] = __builtin_amdgcn_mfma_f32_16x16x32_bf16(af[i], bfr[j], acc[i][j], 0, 0, 0);
    }
    __syncthreads();  // one barrier/step: waits next-tile vmcnt + read-done
    slot ^= 1;
  }

  // ---- epilogue: C/D layout col=lane&15, row=(lane>>4)*4+reg ----
  const size_t boffC = (size_t)blockIdx.z * c_bstride;
#pragma unroll
  for (int i = 0; i < 4; ++i) {
    int row = m0 + wm + i * 16 + lhalf * 4;
#pragma unroll
    for (int j = 0; j < 4; ++j) {
      int col = n0 + wn + j * 16 + lane15;
#pragma unroll
      for (int r = 0; r < 4; ++r) {
        float v = acc[i][j][r];
        if constexpr (OUTM == 0) {
          ((unsigned short*)Cp + boffC)[(size_t)(row + r) * N + col] = f2bf(v);
        } else if constexpr (OUTM == 1) {
          ((unsigned short*)Cp + boffC)[(size_t)(row + r) * N + col] = f2bf(v * scale);
        } else {
          ((float*)Cp + boffC)[(size_t)(row + r) * N + col] = v;
        }
      }
    }
  }
}

// ---------------- row softmax with valid_len masking, in-place on bf16 scores ----------------
// Only cols [0, round_up(vl,64)) are ever read by GEMM3 (CLAMPK) — clamp all
// loads/stores to that range; cols in [vl, round64) get exact 0.
__global__ __launch_bounds__(256) void softmax_kernel(unsigned short* __restrict__ scores,
                                                      const int* __restrict__ valid_lens) {
  const int row = blockIdx.x;
  const int b = row >> 11;  // LQ = 2048
  const int vl = valid_lens[b];
  const int kEnd = (vl + 63) & ~63;  // matches GEMM3's CLAMPK read range
  unsigned short* rp = scores + (size_t)row * LK_;
  const int tid = threadIdx.x;
  const int wid = tid >> 6, lane = tid & 63;
  __shared__ float sred[4];

  const int cb = tid * 8;
  const bool act = cb < kEnd;
  ushortx8 h = {};
  if (act) h = *(const ushortx8*)(rp + cb);
  float x[8];
#pragma unroll
  for (int t = 0; t < 8; ++t) x[t] = bf2f(h[t]);

  float m = -3.4e38f;
#pragma unroll
  for (int t = 0; t < 8; ++t)
    if (cb + t < vl) m = fmaxf(m, x[t]);
#pragma unroll
  for (int off = 32; off >= 1; off >>= 1) m = fmaxf(m, __shfl_xor(m, off));
  if (lane == 0) sred[wid] = m;
  __syncthreads();
  m = fmaxf(fmaxf(sred[0], sred[1]), fmaxf(sred[2], sred[3]));
  __syncthreads();

  float e[8];
  float s = 0.f;
#pragma unroll
  for (int t = 0; t < 8; ++t) {
    e[t] = (cb + t < vl) ? __expf(x[t] - m) : 0.f;
    s += e[t];
  }
#pragma unroll
  for (int off = 32; off >= 1; off >>= 1) s += __shfl_xor(s, off);
  if (lane == 0) sred[wid] = s;
  __syncthreads();
  s = sred[0] + sred[1] + sred[2] + sred[3];
  float inv = 1.f / s;

  if (act) {
    ushortx8 o;
#pragma unroll
    for (int t = 0; t < 8; ++t) o[t] = f2bf(e[t] * inv);
    *(ushortx8*)(rp + cb) = o;
  }
}

extern "C" void kernel_launch(void* const* d_in, const int* in_sizes, int n_in,
                              void* d_out, int out_size, void* d_ws, size_t ws_size,
                              hipStream_t stream) {
  const float* queries = (const float*)d_in[0];    // [8,2048,1024]
  const float* keys = (const float*)d_in[1];       // [8,2048,1024]
  const float* values = (const float*)d_in[2];     // [8,2048,1024]
  const int* valid_lens = (const int*)d_in[3];     // [8]
  const float* W_q = (const float*)d_in[4];        // [1024,1024]
  float* out = (float*)d_out;                      // [8,2048,1024] fp32

  // ws layout (ushort elems):
  //   q_bf    [0, 16M)
  //   scores  [16M, 48M)   (qry_bf aliases this region — dead before GEMM2)
  //   valsT   [48M, 64M)
  //   wqT     [64M, 65M)
  //   keys_bf [65M, 81M)        total 162 MiB
  unsigned short* ws = (unsigned short*)d_ws;
  const size_t M1 = (size_t)1024 * 1024;
  unsigned short* q_bf = ws;
  unsigned short* scores = ws + 16 * M1;
  unsigned short* qry_bf = scores;  // alias
  unsigned short* valsT = ws + 48 * M1;
  unsigned short* wqT = ws + 64 * M1;
  unsigned short* keys_bf = ws + 65 * M1;

  // casts: queries + keys, 16M elems each, in one launch
  cast2_bf16_kernel<<<dim3(16384), 256, 0, stream>>>(queries, qry_bf, keys, keys_bf, 8192);
  // WqT[k][d] = W_q[d][k]  (bf16)
  transpose_cast_kernel<<<dim3(32, 32, 1), dim3(32, 8), 0, stream>>>(
      W_q, wqT, 1024, 1024, 0, 0);
  // valsT[b][v][s] = values[b][s][v]  (bf16)
  transpose_cast_kernel<<<dim3(32, 64, 8), dim3(32, 8), 0, stream>>>(
      values, valsT, 2048, 1024, (long)2048 * 1024, (long)1024 * 2048);
  // GEMM1: q = queries @ W_q -> bf16 [16384,1024]   grid(x=Ntiles, y=Mtiles, z=1)
  gemm_bt_kernel<0, 0, 0><<<dim3(8, 128, 1), 256, 0, stream>>>(
      qry_bf, wqT, q_bf, 16384, 1024, 1024, 0, 0, 0, 1.f, nullptr);
  // GEMM2: scores = q @ keys^T / 32 -> bf16 [8][2048][2048]; skip masked N-tiles
  gemm_bt_kernel<1, 1, 0><<<dim3(16, 16, 8), 256, 0, stream>>>(
      q_bf, keys_bf, scores, 2048, 2048, 1024,
      (long)2048 * 1024, (long)2048 * 1024, (long)2048 * 2048, 0.03125f, valid_lens);
  // softmax rows (masked by valid_lens), in place — writes exact 0 for cols>=vl
  softmax_kernel<<<dim3(B_ * LQ_), 256, 0, stream>>>(scores, valid_lens);
  // GEMM3: out = attn @ values (fp32 epilogue); K-loop clamped to valid_len
  gemm_bt_kernel<2, 0, 1><<<dim3(8, 16, 8), 256, 0, stream>>>(
      scores, valsT, out, 2048, 1024, 2048,
      (long)2048 * 2048, (long)1024 * 2048, (long)2048 * 1024, 1.f, valid_lens);
}

// Round 2
// 406.731 us; speedup vs baseline: 1.0866x; 1.0638x over previous
//
#include <hip/hip_runtime.h>
#include <cstdint>
#include <cstddef>

#define B_   8
#define LQ_  2048
#define LK_  2048

typedef __attribute__((ext_vector_type(8))) __bf16 bf16x8;
typedef __attribute__((ext_vector_type(4))) float f32x4;
typedef __attribute__((ext_vector_type(8))) unsigned short ushortx8;

__device__ __forceinline__ unsigned short f2bf(float f) {
  unsigned u = __builtin_bit_cast(unsigned, f);
  u = u + 0x7fffu + ((u >> 16) & 1u);  // round-to-nearest-even
  return (unsigned short)(u >> 16);
}
__device__ __forceinline__ float bf2f(unsigned short h) {
  unsigned u = ((unsigned)h) << 16;
  return __builtin_bit_cast(float, u);
}

__device__ __forceinline__ void gld_lds16(const void* g, void* l) {
  __builtin_amdgcn_global_load_lds((__attribute__((address_space(1))) void*)(void*)g,
                                   (__attribute__((address_space(3))) void*)l, 16, 0, 0);
}

// ------------- flat cast fp32 -> bf16 for queries+keys in one launch -------------
__global__ __launch_bounds__(256) void cast2_bf16_kernel(
    const float* __restrict__ in0, unsigned short* __restrict__ out0,
    const float* __restrict__ in1, unsigned short* __restrict__ out1,
    size_t half_blocks) {
  const float* in = blockIdx.x < half_blocks ? in0 : in1;
  unsigned short* out = blockIdx.x < half_blocks ? out0 : out1;
  size_t bb = blockIdx.x < half_blocks ? blockIdx.x : blockIdx.x - half_blocks;
  size_t i = (bb * 256 + threadIdx.x) * 8;
  float4 a = *(const float4*)(in + i);
  float4 b = *(const float4*)(in + i + 4);
  ushortx8 o;
  o[0] = f2bf(a.x); o[1] = f2bf(a.y); o[2] = f2bf(a.z); o[3] = f2bf(a.w);
  o[4] = f2bf(b.x); o[5] = f2bf(b.y); o[6] = f2bf(b.z); o[7] = f2bf(b.w);
  *(ushortx8*)(out + i) = o;
}

// ---------------- transpose + cast: fp32 [R][C] -> bf16 [C][R] ----------------
__global__ __launch_bounds__(256) void transpose_cast_kernel(
    const float* __restrict__ in, unsigned short* __restrict__ out,
    int R, int C, long in_bstride, long out_bstride) {
  __shared__ float t[32][33];
  const float* inb = in + (size_t)blockIdx.z * in_bstride;
  unsigned short* outb = out + (size_t)blockIdx.z * out_bstride;
  int c0 = blockIdx.x * 32, r0 = blockIdx.y * 32;
  int tx = threadIdx.x, ty = threadIdx.y;  // block (32,8)
#pragma unroll
  for (int k = 0; k < 4; ++k) {
    int r = ty + k * 8;
    t[r][tx] = inb[(size_t)(r0 + r) * C + c0 + tx];
  }
  __syncthreads();
#pragma unroll
  for (int k = 0; k < 4; ++k) {
    int c = ty + k * 8;
    outb[(size_t)(c0 + c) * R + r0 + tx] = f2bf(t[tx][c]);
  }
}

// ================= 256x256 phase-interleaved GEMM, counted vmcnt =================
// C[M,N] = A[M,K] @ B[N,K]^T.  8 waves (512 thr), per-wave output 128x64.
// BK=32; LDS ring of 4 K-tiles x (A,B) operand-tiles = 128 KiB.
// Operand-tile LDS layout: [128 rowpairs][64 elems]: LDS row p holds M/N-rows
// {2p, 2p+1} x 32 K-elems, with 16B-chunk XOR swizzle pos = c ^ (p&7)
// (same bank-conflict-free geometry as the verified 128x64 layout; 2-way=free).
// Schedule per K-tile t (consume ring[t&3], stage kt t+2 into ring[(t+2)&3]):
//   phase A: ds_read a-frags(m-half0)+b-frags | stage A(t+2) | barrier |
//            lgkmcnt(0) | 16 MFMA | barrier
//   phase B: ds_read a-frags(m-half1)         | stage B(t+2) | barrier |
//            lgkmcnt(0) | 16 MFMA (reuse b) | vmcnt(4 counted) | barrier
// Invariant: the end-of-kt vmcnt(4) leaves exactly kt t+2's 4 loads in flight,
// proving kt t+1 (issued during t-1) resident before the barrier that opens it.
// No vmcnt(0) in steady state (T4); drain only in the 2-tile tail.
// OUTM: 0 = bf16, 1 = bf16 scaled, 2 = fp32
// SKIPN: early-exit blocks with n0 >= valid_len (output overwritten by softmax)
// CLAMPK: clamp K-loop to round_up(valid_len,64) (A cols beyond are exact 0)
template <int OUTM, int SKIPN, int CLAMPK>
__global__ __launch_bounds__(512, 2) void gemm256_kernel(
    const unsigned short* __restrict__ A, const unsigned short* __restrict__ B,
    void* __restrict__ Cp, int M, int N, int K,
    long a_bstride, long b_bstride, long c_bstride, float scale,
    const int* __restrict__ vlp) {
  __shared__ unsigned short lds[4][2][128 * 64];  // [ring][op A/B][rowpair*64]

  const int tid = threadIdx.x;
  const int wid = tid >> 6;
  const int lane = tid & 63;
  const int lane15 = lane & 15;
  const int lhalf = lane >> 4;

  const int nt = (int)((blockIdx.x + 2 * blockIdx.z) & (gridDim.x - 1));
  const int m0 = blockIdx.y * 256;
  const int n0 = nt * 256;

  int vl = K;
  if constexpr (SKIPN || CLAMPK) vl = vlp[blockIdx.z];
  if constexpr (SKIPN) {
    if (n0 >= vl) return;
  }
  int kEnd = K;
  if constexpr (CLAMPK) {
    int ke = (vl + 63) & ~63;
    kEnd = ke < K ? ke : K;
  }
  const int nKt = kEnd >> 5;  // K-tiles of 32; always >= 2

  const unsigned short* Ab = A + (size_t)blockIdx.z * a_bstride;
  const unsigned short* Bb = B + (size_t)blockIdx.z * b_bstride;

  // ---- staging precompute: 1024 chunks/operand-tile, 2 per thread ----
  // chunk blk -> LDS pos blk*16B; holds src chunk c = (blk&7)^((blk>>3)&7)
  // of rowpair p=blk>>3  =>  src row = 2p + (c>>2), src col = (c&3)*8.
  int srowA[2], srowB[2], scol[2], sdst[2];
#pragma unroll
  for (int j = 0; j < 2; ++j) {
    int blk = (wid * 2 + j) * 64 + lane;  // wave-uniform base + lane (gld_lds req)
    int p = blk >> 3, q = blk & 7;
    int c = q ^ (p & 7);
    int r = 2 * p + (c >> 2);
    scol[j] = (c & 3) * 8;
    srowA[j] = m0 + r;
    srowB[j] = n0 + r;
    sdst[j] = blk * 8;
  }

  // ---- read precompute ----
  const int om = (wid >> 2) * 128;  // wave M origin in tile
  const int on = (wid & 3) * 64;    // wave N origin in tile
  // chunk pos for (row r, kchunk lhalf): ((r&1)*4 + lhalf) ^ ((r>>1)&7);
  // r&1 == lane15&1, (r>>1)&7 == (lane15>>1)&7 for 16-aligned frag bases.
  const int swz8 = ((((lane15 & 1) << 2) + lhalf) ^ ((lane15 >> 1) & 7)) << 3;
  const int aBase = ((om >> 1) + (lane15 >> 1)) * 64 + swz8;
  const int bBase = ((on >> 1) + (lane15 >> 1)) * 64 + swz8;

  f32x4 acc[8][4];
#pragma unroll
  for (int f = 0; f < 8; ++f)
#pragma unroll
    for (int g = 0; g < 4; ++g) acc[f][g] = (f32x4){0.f, 0.f, 0.f, 0.f};

  // ---- prologue: stage kt0, kt1; counted wait leaves kt1's B in flight ----
#pragma unroll
  for (int j = 0; j < 2; ++j)
    gld_lds16(Ab + (size_t)srowA[j] * K + scol[j], &lds[0][0][sdst[j]]);
#pragma unroll
  for (int j = 0; j < 2; ++j)
    gld_lds16(Bb + (size_t)srowB[j] * K + scol[j], &lds[0][1][sdst[j]]);
#pragma unroll
  for (int j = 0; j < 2; ++j)
    gld_lds16(Ab + (size_t)srowA[j] * K + (32 + scol[j]), &lds[1][0][sdst[j]]);
#pragma unroll
  for (int j = 0; j < 2; ++j)
    gld_lds16(Bb + (size_t)srowB[j] * K + (32 + scol[j]), &lds[1][1][sdst[j]]);
  asm volatile("s_waitcnt vmcnt(4)" ::: "memory");  // kt0 resident
  __builtin_amdgcn_s_barrier();

  for (int t = 0; t < nKt; ++t) {
    const unsigned short* lA = &lds[t & 3][0][0];
    const unsigned short* lB = &lds[t & 3][1][0];
    const bool st = (t + 2) < nKt;
    const int nb = (t + 2) & 3;
    const int kc = (t + 2) * 32;

    // ---------- phase A: m-half 0 ----------
    bf16x8 a0[4], b0[4];
#pragma unroll
    for (int f = 0; f < 4; ++f) a0[f] = *(const bf16x8*)&lA[aBase + f * 512];
#pragma unroll
    for (int g = 0; g < 4; ++g) b0[g] = *(const bf16x8*)&lB[bBase + g * 512];
    if (st) {
#pragma unroll
      for (int j = 0; j < 2; ++j)
        gld_lds16(Ab + (size_t)srowA[j] * K + (kc + scol[j]), &lds[nb][0][sdst[j]]);
    }
    __builtin_amdgcn_s_barrier();
    asm volatile("s_waitcnt lgkmcnt(0)" ::: "memory");
    __builtin_amdgcn_sched_barrier(0);
    __builtin_amdgcn_s_setprio(1);
#pragma unroll
    for (int f = 0; f < 4; ++f)
#pragma unroll
      for (int g = 0; g < 4; ++g)
        acc[f][g] = __builtin_amdgcn_mfma_f32_16x16x32_bf16(a0[f], b0[g], acc[f][g], 0, 0, 0);
    __builtin_amdgcn_s_setprio(0);
    __builtin_amdgcn_s_barrier();

    // ---------- phase B: m-half 1 (reuse b0) ----------
    bf16x8 a1[4];
#pragma unroll
    for (int f = 0; f < 4; ++f) a1[f] = *(const bf16x8*)&lA[aBase + (f + 4) * 512];
    if (st) {
#pragma unroll
      for (int j = 0; j < 2; ++j)
        gld_lds16(Bb + (size_t)srowB[j] * K + (kc + scol[j]), &lds[nb][1][sdst[j]]);
    }
    __builtin_amdgcn_s_barrier();
    asm volatile("s_waitcnt lgkmcnt(0)" ::: "memory");
    __builtin_amdgcn_sched_barrier(0);
    __builtin_amdgcn_s_setprio(1);
#pragma unroll
    for (int f = 0; f < 4; ++f)
#pragma unroll
      for (int g = 0; g < 4; ++g)
        acc[f + 4][g] = __builtin_amdgcn_mfma_f32_16x16x32_bf16(a1[f], b0[g], acc[f + 4][g], 0, 0, 0);
    __builtin_amdgcn_s_setprio(0);
    if (st)
      asm volatile("s_waitcnt vmcnt(4)" ::: "memory");  // counted: kt t+1 proven done
    else
      asm volatile("s_waitcnt vmcnt(0)" ::: "memory");  // tail drain
    __builtin_amdgcn_s_barrier();
  }

  // ---- epilogue: C/D layout col=lane&15, row=(lane>>4)*4+reg ----
  const size_t boffC = (size_t)blockIdx.z * c_bstride;
#pragma unroll
  for (int f = 0; f < 8; ++f) {
    int row = m0 + om + f * 16 + lhalf * 4;
#pragma unroll
    for (int g = 0; g < 4; ++g) {
      int col = n0 + on + g * 16 + lane15;
#pragma unroll
      for (int r = 0; r < 4; ++r) {
        float v = acc[f][g][r];
        if constexpr (OUTM == 0) {
          ((unsigned short*)Cp + boffC)[(size_t)(row + r) * N + col] = f2bf(v);
        } else if constexpr (OUTM == 1) {
          ((unsigned short*)Cp + boffC)[(size_t)(row + r) * N + col] = f2bf(v * scale);
        } else {
          ((float*)Cp + boffC)[(size_t)(row + r) * N + col] = v;
        }
      }
    }
  }
}

// ---------------- row softmax with valid_len masking, in-place on bf16 scores ----------------
// Only cols [0, round_up(vl,64)) are ever read by GEMM3 (CLAMPK) — clamp all
// loads/stores to that range; cols in [vl, round64) get exact 0.
__global__ __launch_bounds__(256) void softmax_kernel(unsigned short* __restrict__ scores,
                                                      const int* __restrict__ valid_lens) {
  const int row = blockIdx.x;
  const int b = row >> 11;  // LQ = 2048
  const int vl = valid_lens[b];
  const int kEnd = (vl + 63) & ~63;  // matches GEMM3's CLAMPK read range
  unsigned short* rp = scores + (size_t)row * LK_;
  const int tid = threadIdx.x;
  const int wid = tid >> 6, lane = tid & 63;
  __shared__ float sred[4];

  const int cb = tid * 8;
  const bool act = cb < kEnd;
  ushortx8 h = {};
  if (act) h = *(const ushortx8*)(rp + cb);
  float x[8];
#pragma unroll
  for (int t = 0; t < 8; ++t) x[t] = bf2f(h[t]);

  float m = -3.4e38f;
#pragma unroll
  for (int t = 0; t < 8; ++t)
    if (cb + t < vl) m = fmaxf(m, x[t]);
#pragma unroll
  for (int off = 32; off >= 1; off >>= 1) m = fmaxf(m, __shfl_xor(m, off));
  if (lane == 0) sred[wid] = m;
  __syncthreads();
  m = fmaxf(fmaxf(sred[0], sred[1]), fmaxf(sred[2], sred[3]));
  __syncthreads();

  float e[8];
  float s = 0.f;
#pragma unroll
  for (int t = 0; t < 8; ++t) {
    e[t] = (cb + t < vl) ? __expf(x[t] - m) : 0.f;
    s += e[t];
  }
#pragma unroll
  for (int off = 32; off >= 1; off >>= 1) s += __shfl_xor(s, off);
  if (lane == 0) sred[wid] = s;
  __syncthreads();
  s = sred[0] + sred[1] + sred[2] + sred[3];
  float inv = 1.f / s;

  if (act) {
    ushortx8 o;
#pragma unroll
    for (int t = 0; t < 8; ++t) o[t] = f2bf(e[t] * inv);
    *(ushortx8*)(rp + cb) = o;
  }
}

extern "C" void kernel_launch(void* const* d_in, const int* in_sizes, int n_in,
                              void* d_out, int out_size, void* d_ws, size_t ws_size,
                              hipStream_t stream) {
  const float* queries = (const float*)d_in[0];    // [8,2048,1024]
  const float* keys = (const float*)d_in[1];       // [8,2048,1024]
  const float* values = (const float*)d_in[2];     // [8,2048,1024]
  const int* valid_lens = (const int*)d_in[3];     // [8]
  const float* W_q = (const float*)d_in[4];        // [1024,1024]
  float* out = (float*)d_out;                      // [8,2048,1024] fp32

  // ws layout (ushort elems):
  //   q_bf    [0, 16M)
  //   scores  [16M, 48M)   (qry_bf aliases this region — dead before GEMM2)
  //   valsT   [48M, 64M)
  //   wqT     [64M, 65M)
  //   keys_bf [65M, 81M)        total 162 MiB
  unsigned short* ws = (unsigned short*)d_ws;
  const size_t M1 = (size_t)1024 * 1024;
  unsigned short* q_bf = ws;
  unsigned short* scores = ws + 16 * M1;
  unsigned short* qry_bf = scores;  // alias
  unsigned short* valsT = ws + 48 * M1;
  unsigned short* wqT = ws + 64 * M1;
  unsigned short* keys_bf = ws + 65 * M1;

  // casts: queries + keys, 16M elems each, in one launch
  cast2_bf16_kernel<<<dim3(16384), 256, 0, stream>>>(queries, qry_bf, keys, keys_bf, 8192);
  // WqT[k][d] = W_q[d][k]  (bf16)
  transpose_cast_kernel<<<dim3(32, 32, 1), dim3(32, 8), 0, stream>>>(
      W_q, wqT, 1024, 1024, 0, 0);
  // valsT[b][v][s] = values[b][s][v]  (bf16)
  transpose_cast_kernel<<<dim3(32, 64, 8), dim3(32, 8), 0, stream>>>(
      values, valsT, 2048, 1024, (long)2048 * 1024, (long)1024 * 2048);
  // GEMM1: q = queries @ W_q -> bf16 [16384,1024]
  gemm256_kernel<0, 0, 0><<<dim3(4, 64, 1), 512, 0, stream>>>(
      qry_bf, wqT, q_bf, 16384, 1024, 1024, 0, 0, 0, 1.f, nullptr);
  // GEMM2: scores = q @ keys^T / 32 -> bf16 [8][2048][2048]; skip masked N-tiles
  gemm256_kernel<1, 1, 0><<<dim3(8, 8, 8), 512, 0, stream>>>(
      q_bf, keys_bf, scores, 2048, 2048, 1024,
      (long)2048 * 1024, (long)2048 * 1024, (long)2048 * 2048, 0.03125f, valid_lens);
  // softmax rows (masked by valid_lens), in place — writes exact 0 for cols>=vl
  softmax_kernel<<<dim3(B_ * LQ_), 256, 0, stream>>>(scores, valid_lens);
  // GEMM3: out = attn @ values (fp32 epilogue); K-loop clamped to valid_len
  gemm256_kernel<2, 0, 1><<<dim3(4, 8, 8), 512, 0, stream>>>(
      scores, valsT, out, 2048, 1024, 2048,
      (long)2048 * 2048, (long)1024 * 2048, (long)2048 * 1024, 1.f, valid_lens);
}

// Round 3
// 381.304 us; speedup vs baseline: 1.1590x; 1.0667x over previous
//
#include <hip/hip_runtime.h>
#include <cstdint>
#include <cstddef>

#define B_   8
#define LQ_  2048
#define LK_  2048

typedef __attribute__((ext_vector_type(8))) __bf16 bf16x8;
typedef __attribute__((ext_vector_type(4))) float f32x4;
typedef __attribute__((ext_vector_type(8))) unsigned short ushortx8;

__device__ __forceinline__ unsigned short f2bf(float f) {
  unsigned u = __builtin_bit_cast(unsigned, f);
  u = u + 0x7fffu + ((u >> 16) & 1u);  // round-to-nearest-even
  return (unsigned short)(u >> 16);
}
__device__ __forceinline__ float bf2f(unsigned short h) {
  unsigned u = ((unsigned)h) << 16;
  return __builtin_bit_cast(float, u);
}

__device__ __forceinline__ void gld_lds16(const void* g, void* l) {
  __builtin_amdgcn_global_load_lds((__attribute__((address_space(1))) void*)(void*)g,
                                   (__attribute__((address_space(3))) void*)l, 16, 0, 0);
}

// ------------- flat cast fp32 -> bf16: queries + keys(row-clamped) + W_q -------------
// grid regions: [0,8192) queries, [8192,16384) keys, [16384,16896) W_q.
// keys rows >= round256(vl[b]) are never read (GEMM1' skips those M-tiles) -> skip cast.
__global__ __launch_bounds__(256) void cast3_bf16_kernel(
    const float* __restrict__ q, unsigned short* __restrict__ qo,
    const float* __restrict__ k, unsigned short* __restrict__ ko,
    const float* __restrict__ w, unsigned short* __restrict__ wo,
    const int* __restrict__ vlp) {
  int bb = (int)blockIdx.x;
  const float* in;
  unsigned short* out;
  if (bb < 8192) {
    in = q; out = qo;
  } else if (bb < 16384) {
    bb -= 8192;
    in = k; out = ko;
    int batch = bb >> 10;            // 1024 blocks per batch (2048x1024 elems)
    int row = (bb & 1023) * 2;       // 2 rows per block
    int vl = vlp[batch];
    if (row >= ((vl + 255) & ~255)) return;
  } else {
    bb -= 16384;
    in = w; out = wo;
  }
  size_t i = ((size_t)bb * 256 + threadIdx.x) * 8;
  float4 a = *(const float4*)(in + i);
  float4 b = *(const float4*)(in + i + 4);
  ushortx8 o;
  o[0] = f2bf(a.x); o[1] = f2bf(a.y); o[2] = f2bf(a.z); o[3] = f2bf(a.w);
  o[4] = f2bf(b.x); o[5] = f2bf(b.y); o[6] = f2bf(b.z); o[7] = f2bf(b.w);
  *(ushortx8*)(out + i) = o;
}

// ---------------- transpose + cast: fp32 [R][C] -> bf16 [C][R] ----------------
// vlp != nullptr: skip row-tiles with r0 >= round64(vl[z]) (GEMM3 never reads them).
__global__ __launch_bounds__(256) void transpose_cast_kernel(
    const float* __restrict__ in, unsigned short* __restrict__ out,
    int R, int C, long in_bstride, long out_bstride, const int* __restrict__ vlp) {
  __shared__ float t[32][33];
  int r0 = blockIdx.y * 32;
  if (vlp) {
    int kEnd = (vlp[blockIdx.z] + 63) & ~63;
    if (r0 >= kEnd) return;
  }
  const float* inb = in + (size_t)blockIdx.z * in_bstride;
  unsigned short* outb = out + (size_t)blockIdx.z * out_bstride;
  int c0 = blockIdx.x * 32;
  int tx = threadIdx.x, ty = threadIdx.y;  // block (32,8)
#pragma unroll
  for (int k = 0; k < 4; ++k) {
    int r = ty + k * 8;
    t[r][tx] = inb[(size_t)(r0 + r) * C + c0 + tx];
  }
  __syncthreads();
#pragma unroll
  for (int k = 0; k < 4; ++k) {
    int c = ty + k * 8;
    outb[(size_t)(c0 + c) * R + r0 + tx] = f2bf(t[tx][c]);
  }
}

// ================= 256x256 phase-interleaved GEMM, depth-3 counted vmcnt =================
// C[M,N] = A[M,K] @ B[N,K]^T.  8 waves (512 thr), per-wave output 128x64.
// BK=32; LDS ring of 4 K-tiles x (A,B) operand-tiles = 128 KiB.
// Operand-tile LDS layout: [128 rowpairs][64 elems] with 16B-chunk XOR swizzle
// pos = c ^ (p&7) (bank-conflict-free, verified rounds 0-2).
// Schedule per K-tile t (consume ring[t&3], stage kt t+3 into ring[(t+3)&3]):
//   phase A: ds_read a0,b0 | stage A(t+3) | barrier | lgkm(0) | 16 MFMA | barrier
//   phase B: ds_read a1    | stage B(t+3) | barrier | lgkm(0) | 16 MFMA |
//            vmcnt(4*pend) | barrier
// Steady state pend=2 -> vmcnt(8): drains exactly tile t+1 (its 4 loads are the
// oldest of the <=12 outstanding), leaving t+2,t+3 in flight. Loads are thus
// issued 3 tiles (6 phases) before consumption. Drain narrows in the tail.
// OUTM: 0 = bf16, 1 = bf16 scaled, 2 = fp32
// SKIPN: skip blocks with n0 >= vl;  SKIPM: skip blocks with m0 >= vl
// CLAMPK: clamp K-loop to round_up(valid_len,64)
template <int OUTM, int SKIPN, int SKIPM, int CLAMPK>
__global__ __launch_bounds__(512, 2) void gemm256_kernel(
    const unsigned short* __restrict__ A, const unsigned short* __restrict__ B,
    void* __restrict__ Cp, int M, int N, int K,
    long a_bstride, long b_bstride, long c_bstride, float scale,
    const int* __restrict__ vlp) {
  __shared__ unsigned short lds[4][2][128 * 64];  // [ring][op A/B][rowpair*64]

  const int tid = threadIdx.x;
  const int wid = tid >> 6;
  const int lane = tid & 63;
  const int lane15 = lane & 15;
  const int lhalf = lane >> 4;

  const int nt = (int)((blockIdx.x + 2 * blockIdx.z) & (gridDim.x - 1));
  const int m0 = blockIdx.y * 256;
  const int n0 = nt * 256;

  int vl = K;
  if constexpr (SKIPN || SKIPM || CLAMPK) vl = vlp[blockIdx.z];
  if constexpr (SKIPN) {
    if (n0 >= vl) return;
  }
  if constexpr (SKIPM) {
    if (m0 >= vl) return;
  }
  int kEnd = K;
  if constexpr (CLAMPK) {
    int ke = (vl + 63) & ~63;
    kEnd = ke < K ? ke : K;
  }
  const int nKt = kEnd >> 5;  // K-tiles of 32; always >= 2

  const unsigned short* Ab = A + (size_t)blockIdx.z * a_bstride;
  const unsigned short* Bb = B + (size_t)blockIdx.z * b_bstride;

  // ---- staging precompute: 1024 chunks/operand-tile, 2 per thread ----
  int srowA[2], srowB[2], scol[2], sdst[2];
#pragma unroll
  for (int j = 0; j < 2; ++j) {
    int blk = (wid * 2 + j) * 64 + lane;  // wave-uniform base + lane (gld_lds req)
    int p = blk >> 3, q = blk & 7;
    int c = q ^ (p & 7);
    int r = 2 * p + (c >> 2);
    scol[j] = (c & 3) * 8;
    srowA[j] = m0 + r;
    srowB[j] = n0 + r;
    sdst[j] = blk * 8;
  }

  // ---- read precompute ----
  const int om = (wid >> 2) * 128;  // wave M origin in tile
  const int on = (wid & 3) * 64;    // wave N origin in tile
  const int swz8 = ((((lane15 & 1) << 2) + lhalf) ^ ((lane15 >> 1) & 7)) << 3;
  const int aBase = ((om >> 1) + (lane15 >> 1)) * 64 + swz8;
  const int bBase = ((on >> 1) + (lane15 >> 1)) * 64 + swz8;

  f32x4 acc[8][4];
#pragma unroll
  for (int f = 0; f < 8; ++f)
#pragma unroll
    for (int g = 0; g < 4; ++g) acc[f][g] = (f32x4){0.f, 0.f, 0.f, 0.f};

  // ---- prologue: stage kt0..kt2 (depth 3); counted wait -> kt0 resident ----
#pragma unroll
  for (int j = 0; j < 2; ++j)
    gld_lds16(Ab + (size_t)srowA[j] * K + scol[j], &lds[0][0][sdst[j]]);
#pragma unroll
  for (int j = 0; j < 2; ++j)
    gld_lds16(Bb + (size_t)srowB[j] * K + scol[j], &lds[0][1][sdst[j]]);
#pragma unroll
  for (int j = 0; j < 2; ++j)
    gld_lds16(Ab + (size_t)srowA[j] * K + (32 + scol[j]), &lds[1][0][sdst[j]]);
#pragma unroll
  for (int j = 0; j < 2; ++j)
    gld_lds16(Bb + (size_t)srowB[j] * K + (32 + scol[j]), &lds[1][1][sdst[j]]);
  if (nKt > 2) {
#pragma unroll
    for (int j = 0; j < 2; ++j)
      gld_lds16(Ab + (size_t)srowA[j] * K + (64 + scol[j]), &lds[2][0][sdst[j]]);
#pragma unroll
    for (int j = 0; j < 2; ++j)
      gld_lds16(Bb + (size_t)srowB[j] * K + (64 + scol[j]), &lds[2][1][sdst[j]]);
    asm volatile("s_waitcnt vmcnt(8)" ::: "memory");  // kt0 resident, kt1/kt2 in flight
  } else {
    asm volatile("s_waitcnt vmcnt(4)" ::: "memory");  // kt0 resident, kt1 in flight
  }
  __builtin_amdgcn_s_barrier();

  for (int t = 0; t < nKt; ++t) {
    const unsigned short* lA = &lds[t & 3][0][0];
    const unsigned short* lB = &lds[t & 3][1][0];
    const bool st = (t + 3) < nKt;
    const int nb = (t + 3) & 3;
    const int kc = (t + 3) * 32;

    // ---------- phase A: m-half 0 ----------
    bf16x8 a0[4], b0[4];
#pragma unroll
    for (int f = 0; f < 4; ++f) a0[f] = *(const bf16x8*)&lA[aBase + f * 512];
#pragma unroll
    for (int g = 0; g < 4; ++g) b0[g] = *(const bf16x8*)&lB[bBase + g * 512];
    if (st) {
#pragma unroll
      for (int j = 0; j < 2; ++j)
        gld_lds16(Ab + (size_t)srowA[j] * K + (kc + scol[j]), &lds[nb][0][sdst[j]]);
    }
    __builtin_amdgcn_s_barrier();
    asm volatile("s_waitcnt lgkmcnt(0)" ::: "memory");
    __builtin_amdgcn_sched_barrier(0);
    __builtin_amdgcn_s_setprio(1);
#pragma unroll
    for (int f = 0; f < 4; ++f)
#pragma unroll
      for (int g = 0; g < 4; ++g)
        acc[f][g] = __builtin_amdgcn_mfma_f32_16x16x32_bf16(a0[f], b0[g], acc[f][g], 0, 0, 0);
    __builtin_amdgcn_s_setprio(0);
    __builtin_amdgcn_s_barrier();

    // ---------- phase B: m-half 1 (reuse b0) ----------
    bf16x8 a1[4];
#pragma unroll
    for (int f = 0; f < 4; ++f) a1[f] = *(const bf16x8*)&lA[aBase + (f + 4) * 512];
    if (st) {
#pragma unroll
      for (int j = 0; j < 2; ++j)
        gld_lds16(Bb + (size_t)srowB[j] * K + (kc + scol[j]), &lds[nb][1][sdst[j]]);
    }
    __builtin_amdgcn_s_barrier();
    asm volatile("s_waitcnt lgkmcnt(0)" ::: "memory");
    __builtin_amdgcn_sched_barrier(0);
    __builtin_amdgcn_s_setprio(1);
#pragma unroll
    for (int f = 0; f < 4; ++f)
#pragma unroll
      for (int g = 0; g < 4; ++g)
        acc[f + 4][g] = __builtin_amdgcn_mfma_f32_16x16x32_bf16(a1[f], b0[g], acc[f + 4][g], 0, 0, 0);
    __builtin_amdgcn_s_setprio(0);
    // ---- counted wait: ensure kt t+1 resident; pend = staged tiles beyond t+1 ----
    {
      int hi = nKt < t + 4 ? nKt : t + 4;
      int pend = hi - (t + 2);
      if (pend >= 2)
        asm volatile("s_waitcnt vmcnt(8)" ::: "memory");
      else if (pend == 1)
        asm volatile("s_waitcnt vmcnt(4)" ::: "memory");
      else
        asm volatile("s_waitcnt vmcnt(0)" ::: "memory");
    }
    __builtin_amdgcn_s_barrier();
  }

  // ---- epilogue: C/D layout col=lane&15, row=(lane>>4)*4+reg ----
  const size_t boffC = (size_t)blockIdx.z * c_bstride;
#pragma unroll
  for (int f = 0; f < 8; ++f) {
    int row = m0 + om + f * 16 + lhalf * 4;
#pragma unroll
    for (int g = 0; g < 4; ++g) {
      int col = n0 + on + g * 16 + lane15;
#pragma unroll
      for (int r = 0; r < 4; ++r) {
        float v = acc[f][g][r];
        if constexpr (OUTM == 0) {
          ((unsigned short*)Cp + boffC)[(size_t)(row + r) * N + col] = f2bf(v);
        } else if constexpr (OUTM == 1) {
          ((unsigned short*)Cp + boffC)[(size_t)(row + r) * N + col] = f2bf(v * scale);
        } else {
          ((float*)Cp + boffC)[(size_t)(row + r) * N + col] = v;
        }
      }
    }
  }
}

// ---------------- row softmax with valid_len masking, in-place on bf16 scores ----------------
__global__ __launch_bounds__(256) void softmax_kernel(unsigned short* __restrict__ scores,
                                                      const int* __restrict__ valid_lens) {
  const int row = blockIdx.x;
  const int b = row >> 11;  // LQ = 2048
  const int vl = valid_lens[b];
  const int kEnd = (vl + 63) & ~63;  // matches GEMM3's CLAMPK read range
  unsigned short* rp = scores + (size_t)row * LK_;
  const int tid = threadIdx.x;
  const int wid = tid >> 6, lane = tid & 63;
  __shared__ float sred[4];

  const int cb = tid * 8;
  const bool act = cb < kEnd;
  ushortx8 h = {};
  if (act) h = *(const ushortx8*)(rp + cb);
  float x[8];
#pragma unroll
  for (int t = 0; t < 8; ++t) x[t] = bf2f(h[t]);

  float m = -3.4e38f;
#pragma unroll
  for (int t = 0; t < 8; ++t)
    if (cb + t < vl) m = fmaxf(m, x[t]);
#pragma unroll
  for (int off = 32; off >= 1; off >>= 1) m = fmaxf(m, __shfl_xor(m, off));
  if (lane == 0) sred[wid] = m;
  __syncthreads();
  m = fmaxf(fmaxf(sred[0], sred[1]), fmaxf(sred[2], sred[3]));
  __syncthreads();

  float e[8];
  float s = 0.f;
#pragma unroll
  for (int t = 0; t < 8; ++t) {
    e[t] = (cb + t < vl) ? __expf(x[t] - m) : 0.f;
    s += e[t];
  }
#pragma unroll
  for (int off = 32; off >= 1; off >>= 1) s += __shfl_xor(s, off);
  if (lane == 0) sred[wid] = s;
  __syncthreads();
  s = sred[0] + sred[1] + sred[2] + sred[3];
  float inv = 1.f / s;

  if (act) {
    ushortx8 o;
#pragma unroll
    for (int t = 0; t < 8; ++t) o[t] = f2bf(e[t] * inv);
    *(ushortx8*)(rp + cb) = o;
  }
}

extern "C" void kernel_launch(void* const* d_in, const int* in_sizes, int n_in,
                              void* d_out, int out_size, void* d_ws, size_t ws_size,
                              hipStream_t stream) {
  const float* queries = (const float*)d_in[0];    // [8,2048,1024]
  const float* keys = (const float*)d_in[1];       // [8,2048,1024]
  const float* values = (const float*)d_in[2];     // [8,2048,1024]
  const int* valid_lens = (const int*)d_in[3];     // [8]
  const float* W_q = (const float*)d_in[4];        // [1024,1024]
  float* out = (float*)d_out;                      // [8,2048,1024] fp32

  // Re-association: scores = Q @ (K @ W^T)^T — project KEYS (maskable), not queries.
  // ws layout (ushort elems), total 81M = 162 MiB:
  //   q_bf    [0, 16M)      queries bf16
  //   scores  [16M, 48M)
  //   keysP   [48M, 64M)    K@W^T bf16; dead after GEMM2 -> valsT aliases it
  //   w_bf    [64M, 65M)    W_q bf16 row-major (= B^T operand as-is)
  //   keys_bf [65M, 81M)
  unsigned short* ws = (unsigned short*)d_ws;
  const size_t M1 = (size_t)1024 * 1024;
  unsigned short* q_bf = ws;
  unsigned short* scores = ws + 16 * M1;
  unsigned short* keysP = ws + 48 * M1;
  unsigned short* valsT = keysP;  // alias — transpose runs after GEMM2
  unsigned short* w_bf = ws + 64 * M1;
  unsigned short* keys_bf = ws + 65 * M1;

  // casts: queries + keys(row-clamped to round256(vl)) + W_q
  cast3_bf16_kernel<<<dim3(16896), 256, 0, stream>>>(
      queries, q_bf, keys, keys_bf, W_q, w_bf, valid_lens);
  // GEMM1': keysP[b] = keys_bf[b] @ W_q^T -> bf16 [2048,1024]; skip m-tiles >= vl
  gemm256_kernel<0, 0, 1, 0><<<dim3(4, 8, 8), 512, 0, stream>>>(
      keys_bf, w_bf, keysP, 2048, 1024, 1024,
      (long)2048 * 1024, 0, (long)2048 * 1024, 1.f, valid_lens);
  // GEMM2': scores = q_bf @ keysP^T / 32 -> bf16 [8][2048][2048]; skip masked n-tiles
  gemm256_kernel<1, 1, 0, 0><<<dim3(8, 8, 8), 512, 0, stream>>>(
      q_bf, keysP, scores, 2048, 2048, 1024,
      (long)2048 * 1024, (long)2048 * 1024, (long)2048 * 2048, 0.03125f, valid_lens);
  // valsT[b][v][s] = values[b][s][v] (bf16), s-tiles clamped to round64(vl).
  // Runs after GEMM2 (valsT aliases keysP).
  transpose_cast_kernel<<<dim3(32, 64, 8), dim3(32, 8), 0, stream>>>(
      values, valsT, 2048, 1024, (long)2048 * 1024, (long)1024 * 2048, valid_lens);
  // softmax rows (masked by valid_lens), in place — writes exact 0 for cols>=vl
  softmax_kernel<<<dim3(B_ * LQ_), 256, 0, stream>>>(scores, valid_lens);
  // GEMM3: out = attn @ values (fp32 epilogue); K-loop clamped to valid_len
  gemm256_kernel<2, 0, 0, 1><<<dim3(4, 8, 8), 512, 0, stream>>>(
      scores, valsT, out, 2048, 1024, 2048,
      (long)2048 * 2048, (long)1024 * 2048, (long)2048 * 1024, 1.f, valid_lens);
}

// Round 4
// 361.454 us; speedup vs baseline: 1.2227x; 1.0549x over previous
//
#include <hip/hip_runtime.h>
#include <cstdint>
#include <cstddef>

#define B_   8
#define LQ_  2048
#define LK_  2048

typedef __attribute__((ext_vector_type(8))) __bf16 bf16x8;
typedef __attribute__((ext_vector_type(4))) float f32x4;
typedef __attribute__((ext_vector_type(8))) unsigned short ushortx8;

__device__ __forceinline__ unsigned short f2bf(float f) {
  unsigned u = __builtin_bit_cast(unsigned, f);
  u = u + 0x7fffu + ((u >> 16) & 1u);  // round-to-nearest-even
  return (unsigned short)(u >> 16);
}
__device__ __forceinline__ float bf2f(unsigned short h) {
  unsigned u = ((unsigned)h) << 16;
  return __builtin_bit_cast(float, u);
}

__device__ __forceinline__ void gld_lds16(const void* g, void* l) {
  __builtin_amdgcn_global_load_lds((__attribute__((address_space(1))) void*)(void*)g,
                                   (__attribute__((address_space(3))) void*)l, 16, 0, 0);
}

// ------------- flat cast fp32 -> bf16: queries + keys(row-clamped) + W_q -------------
__global__ __launch_bounds__(256) void cast3_bf16_kernel(
    const float* __restrict__ q, unsigned short* __restrict__ qo,
    const float* __restrict__ k, unsigned short* __restrict__ ko,
    const float* __restrict__ w, unsigned short* __restrict__ wo,
    const int* __restrict__ vlp) {
  int bb = (int)blockIdx.x;
  const float* in;
  unsigned short* out;
  if (bb < 8192) {
    in = q; out = qo;
  } else if (bb < 16384) {
    bb -= 8192;
    in = k; out = ko;
    int batch = bb >> 10;            // 1024 blocks per batch (2048x1024 elems)
    int row = (bb & 1023) * 2;       // 2 rows per block
    int vl = vlp[batch];
    if (row >= ((vl + 255) & ~255)) return;
  } else {
    bb -= 16384;
    in = w; out = wo;
  }
  size_t i = ((size_t)bb * 256 + threadIdx.x) * 8;
  float4 a = *(const float4*)(in + i);
  float4 b = *(const float4*)(in + i + 4);
  ushortx8 o;
  o[0] = f2bf(a.x); o[1] = f2bf(a.y); o[2] = f2bf(a.z); o[3] = f2bf(a.w);
  o[4] = f2bf(b.x); o[5] = f2bf(b.y); o[6] = f2bf(b.z); o[7] = f2bf(b.w);
  *(ushortx8*)(out + i) = o;
}

// ---------------- transpose + cast: fp32 [R][C] -> bf16 [C][R] ----------------
__global__ __launch_bounds__(256) void transpose_cast_kernel(
    const float* __restrict__ in, unsigned short* __restrict__ out,
    int R, int C, long in_bstride, long out_bstride, const int* __restrict__ vlp) {
  __shared__ float t[32][33];
  int r0 = blockIdx.y * 32;
  if (vlp) {
    int kEnd = (vlp[blockIdx.z] + 63) & ~63;
    if (r0 >= kEnd) return;
  }
  const float* inb = in + (size_t)blockIdx.z * in_bstride;
  unsigned short* outb = out + (size_t)blockIdx.z * out_bstride;
  int c0 = blockIdx.x * 32;
  int tx = threadIdx.x, ty = threadIdx.y;  // block (32,8)
#pragma unroll
  for (int k = 0; k < 4; ++k) {
    int r = ty + k * 8;
    t[r][tx] = inb[(size_t)(r0 + r) * C + c0 + tx];
  }
  __syncthreads();
#pragma unroll
  for (int k = 0; k < 4; ++k) {
    int c = ty + k * 8;
    outb[(size_t)(c0 + c) * R + r0 + tx] = f2bf(t[tx][c]);
  }
}

// ================= 256x256 GEMM, reg-dbuf fragments + counted vmcnt =================
// C[M,N] = A[M,K] @ B[N,K]^T.  8 waves (512 thr), per-wave output 128x64.
// BK=32; LDS ring of 4 K-tiles x (A,B) = 128 KiB, 16B-chunk XOR swizzle (0-conflict).
// K-tile iter t (ONE barrier per tile; fragments register-double-buffered):
//   phA: issue a1(t) ds_reads + stage A(t+3) | MFMA half0 (preloaded a0,b0) | lgkm(0)
//   phB: issue a0,b0(t+1) ds_reads + stage B(t+3) | MFMA half1 (a1 x b0) |
//        lgkm(0) | vmcnt(4) | s_barrier
// Hazards: stage(t+3) hits slot (t-1)&3 — its last reads (a1(t-1)) are lgkm'd before
// the iter-(t-1) barrier. Phase-B reads slot t+1 — the collective vmcnt(4)+barrier at
// end of iter t-1 proves tiles <= t+1 resident (only t+2's 4 loads left in flight).
// Loop unrolled x2 with ping-pong register names (nKt even: kEnd is 64-rounded).
#define KT_ITER(T, CA0, CB0, NA0, NB0)                                          \
  {                                                                             \
    const unsigned short* lA = &lds[(T) & 3][0][0];                             \
    const unsigned short* lAn = &lds[((T) + 1) & 3][0][0];                      \
    const unsigned short* lBn = &lds[((T) + 1) & 3][1][0];                      \
    const bool st = (T) + 3 < nKt;                                              \
    const int nb = ((T) + 3) & 3;                                               \
    const int kc = ((T) + 3) * 32;                                              \
    const bool rd = (T) + 1 < nKt;                                              \
    bf16x8 a1[4];                                                               \
    _Pragma("unroll")                                                           \
    for (int f = 0; f < 4; ++f)                                                 \
      a1[f] = *(const bf16x8*)&lA[aBase + (f + 4) * 512];                       \
    if (st) {                                                                   \
      _Pragma("unroll")                                                         \
      for (int j = 0; j < 2; ++j)                                               \
        gld_lds16(Ab + (size_t)srowA[j] * K + (kc + scol[j]),                   \
                  &lds[nb][0][sdst[j]]);                                        \
    }                                                                           \
    __builtin_amdgcn_sched_barrier(0);                                          \
    __builtin_amdgcn_s_setprio(1);                                              \
    _Pragma("unroll")                                                           \
    for (int f = 0; f < 4; ++f) {                                               \
      _Pragma("unroll")                                                         \
      for (int g = 0; g < 4; ++g)                                               \
        acc[f][g] = __builtin_amdgcn_mfma_f32_16x16x32_bf16(CA0[f], CB0[g],     \
                                                            acc[f][g], 0, 0, 0);\
    }                                                                           \
    __builtin_amdgcn_s_setprio(0);                                              \
    asm volatile("s_waitcnt lgkmcnt(0)" ::: "memory");                          \
    __builtin_amdgcn_sched_barrier(0);                                          \
    if (rd) {                                                                   \
      _Pragma("unroll")                                                         \
      for (int f = 0; f < 4; ++f)                                               \
        NA0[f] = *(const bf16x8*)&lAn[aBase + f * 512];                         \
      _Pragma("unroll")                                                         \
      for (int g = 0; g < 4; ++g)                                               \
        NB0[g] = *(const bf16x8*)&lBn[bBase + g * 512];                         \
    }                                                                           \
    if (st) {                                                                   \
      _Pragma("unroll")                                                         \
      for (int j = 0; j < 2; ++j)                                               \
        gld_lds16(Bb + (size_t)srowB[j] * K + (kc + scol[j]),                   \
                  &lds[nb][1][sdst[j]]);                                        \
    }                                                                           \
    __builtin_amdgcn_sched_barrier(0);                                          \
    __builtin_amdgcn_s_setprio(1);                                              \
    _Pragma("unroll")                                                           \
    for (int f = 0; f < 4; ++f) {                                               \
      _Pragma("unroll")                                                         \
      for (int g = 0; g < 4; ++g)                                               \
        acc[f + 4][g] = __builtin_amdgcn_mfma_f32_16x16x32_bf16(                \
            a1[f], CB0[g], acc[f + 4][g], 0, 0, 0);                             \
    }                                                                           \
    __builtin_amdgcn_s_setprio(0);                                              \
    asm volatile("s_waitcnt lgkmcnt(0)" ::: "memory");                          \
    if (st)                                                                     \
      asm volatile("s_waitcnt vmcnt(4)" ::: "memory");                          \
    else                                                                        \
      asm volatile("s_waitcnt vmcnt(0)" ::: "memory");                          \
    __builtin_amdgcn_sched_barrier(0);                                          \
    __builtin_amdgcn_s_barrier();                                               \
  }

// OUTM: 0 = bf16, 1 = bf16 scaled, 2 = fp32
// SKIPN: skip blocks with n0 >= vl;  SKIPM: skip blocks with m0 >= vl
// CLAMPK: clamp K-loop to round_up(valid_len,64)
template <int OUTM, int SKIPN, int SKIPM, int CLAMPK>
__global__ __launch_bounds__(512, 2) void gemm256_kernel(
    const unsigned short* __restrict__ A, const unsigned short* __restrict__ B,
    void* __restrict__ Cp, int M, int N, int K,
    long a_bstride, long b_bstride, long c_bstride, float scale,
    const int* __restrict__ vlp) {
  __shared__ unsigned short lds[4][2][128 * 64];  // [ring][op A/B][rowpair*64]

  const int tid = threadIdx.x;
  const int wid = tid >> 6;
  const int lane = tid & 63;
  const int lane15 = lane & 15;
  const int lhalf = lane >> 4;

  const int nt = (int)((blockIdx.x + 2 * blockIdx.z) & (gridDim.x - 1));
  const int m0 = blockIdx.y * 256;
  const int n0 = nt * 256;

  int vl = K;
  if constexpr (SKIPN || SKIPM || CLAMPK) vl = vlp[blockIdx.z];
  if constexpr (SKIPN) {
    if (n0 >= vl) return;
  }
  if constexpr (SKIPM) {
    if (m0 >= vl) return;
  }
  int kEnd = K;
  if constexpr (CLAMPK) {
    int ke = (vl + 63) & ~63;
    kEnd = ke < K ? ke : K;
  }
  const int nKt = kEnd >> 5;  // K-tiles of 32; even (kEnd is 64-rounded), >= 2

  const unsigned short* Ab = A + (size_t)blockIdx.z * a_bstride;
  const unsigned short* Bb = B + (size_t)blockIdx.z * b_bstride;

  // ---- staging precompute: 1024 chunks/operand-tile, 2 per thread ----
  int srowA[2], srowB[2], scol[2], sdst[2];
#pragma unroll
  for (int j = 0; j < 2; ++j) {
    int blk = (wid * 2 + j) * 64 + lane;  // wave-uniform base + lane (gld_lds req)
    int p = blk >> 3, q = blk & 7;
    int c = q ^ (p & 7);
    int r = 2 * p + (c >> 2);
    scol[j] = (c & 3) * 8;
    srowA[j] = m0 + r;
    srowB[j] = n0 + r;
    sdst[j] = blk * 8;
  }

  // ---- read precompute ----
  const int om = (wid >> 2) * 128;  // wave M origin in tile
  const int on = (wid & 3) * 64;    // wave N origin in tile
  const int swz8 = ((((lane15 & 1) << 2) + lhalf) ^ ((lane15 >> 1) & 7)) << 3;
  const int aBase = ((om >> 1) + (lane15 >> 1)) * 64 + swz8;
  const int bBase = ((on >> 1) + (lane15 >> 1)) * 64 + swz8;

  f32x4 acc[8][4];
#pragma unroll
  for (int f = 0; f < 8; ++f)
#pragma unroll
    for (int g = 0; g < 4; ++g) acc[f][g] = (f32x4){0.f, 0.f, 0.f, 0.f};

  // ---- prologue: stage kt0,kt1,(kt2); wait leaves only kt2 in flight ----
#pragma unroll
  for (int j = 0; j < 2; ++j)
    gld_lds16(Ab + (size_t)srowA[j] * K + scol[j], &lds[0][0][sdst[j]]);
#pragma unroll
  for (int j = 0; j < 2; ++j)
    gld_lds16(Bb + (size_t)srowB[j] * K + scol[j], &lds[0][1][sdst[j]]);
#pragma unroll
  for (int j = 0; j < 2; ++j)
    gld_lds16(Ab + (size_t)srowA[j] * K + (32 + scol[j]), &lds[1][0][sdst[j]]);
#pragma unroll
  for (int j = 0; j < 2; ++j)
    gld_lds16(Bb + (size_t)srowB[j] * K + (32 + scol[j]), &lds[1][1][sdst[j]]);
  if (nKt > 2) {
#pragma unroll
    for (int j = 0; j < 2; ++j)
      gld_lds16(Ab + (size_t)srowA[j] * K + (64 + scol[j]), &lds[2][0][sdst[j]]);
#pragma unroll
    for (int j = 0; j < 2; ++j)
      gld_lds16(Bb + (size_t)srowB[j] * K + (64 + scol[j]), &lds[2][1][sdst[j]]);
    asm volatile("s_waitcnt vmcnt(4)" ::: "memory");  // kt0,kt1 resident
  } else {
    asm volatile("s_waitcnt vmcnt(0)" ::: "memory");
  }
  __builtin_amdgcn_s_barrier();

  // ---- preload tile-0 half-0 fragments into registers ----
  bf16x8 a0X[4], b0X[4], a0Y[4], b0Y[4];
#pragma unroll
  for (int f = 0; f < 4; ++f) a0X[f] = *(const bf16x8*)&lds[0][0][aBase + f * 512];
#pragma unroll
  for (int g = 0; g < 4; ++g) b0X[g] = *(const bf16x8*)&lds[0][1][bBase + g * 512];
  asm volatile("s_waitcnt lgkmcnt(0)" ::: "memory");
  __builtin_amdgcn_sched_barrier(0);

  for (int t = 0; t < nKt; t += 2) {
    KT_ITER(t, a0X, b0X, a0Y, b0Y);
    KT_ITER(t + 1, a0Y, b0Y, a0X, b0X);
  }

  // ---- epilogue: C/D layout col=lane&15, row=(lane>>4)*4+reg ----
  const size_t boffC = (size_t)blockIdx.z * c_bstride;
#pragma unroll
  for (int f = 0; f < 8; ++f) {
    int row = m0 + om + f * 16 + lhalf * 4;
#pragma unroll
    for (int g = 0; g < 4; ++g) {
      int col = n0 + on + g * 16 + lane15;
#pragma unroll
      for (int r = 0; r < 4; ++r) {
        float v = acc[f][g][r];
        if constexpr (OUTM == 0) {
          ((unsigned short*)Cp + boffC)[(size_t)(row + r) * N + col] = f2bf(v);
        } else if constexpr (OUTM == 1) {
          ((unsigned short*)Cp + boffC)[(size_t)(row + r) * N + col] = f2bf(v * scale);
        } else {
          ((float*)Cp + boffC)[(size_t)(row + r) * N + col] = v;
        }
      }
    }
  }
}

// ---------------- row softmax with valid_len masking, in-place on bf16 scores ----------------
__global__ __launch_bounds__(256) void softmax_kernel(unsigned short* __restrict__ scores,
                                                      const int* __restrict__ valid_lens) {
  const int row = blockIdx.x;
  const int b = row >> 11;  // LQ = 2048
  const int vl = valid_lens[b];
  const int kEnd = (vl + 63) & ~63;  // matches GEMM3's CLAMPK read range
  unsigned short* rp = scores + (size_t)row * LK_;
  const int tid = threadIdx.x;
  const int wid = tid >> 6, lane = tid & 63;
  __shared__ float sred[4];

  const int cb = tid * 8;
  const bool act = cb < kEnd;
  ushortx8 h = {};
  if (act) h = *(const ushortx8*)(rp + cb);
  float x[8];
#pragma unroll
  for (int t = 0; t < 8; ++t) x[t] = bf2f(h[t]);

  float m = -3.4e38f;
#pragma unroll
  for (int t = 0; t < 8; ++t)
    if (cb + t < vl) m = fmaxf(m, x[t]);
#pragma unroll
  for (int off = 32; off >= 1; off >>= 1) m = fmaxf(m, __shfl_xor(m, off));
  if (lane == 0) sred[wid] = m;
  __syncthreads();
  m = fmaxf(fmaxf(sred[0], sred[1]), fmaxf(sred[2], sred[3]));
  __syncthreads();

  float e[8];
  float s = 0.f;
#pragma unroll
  for (int t = 0; t < 8; ++t) {
    e[t] = (cb + t < vl) ? __expf(x[t] - m) : 0.f;
    s += e[t];
  }
#pragma unroll
  for (int off = 32; off >= 1; off >>= 1) s += __shfl_xor(s, off);
  if (lane == 0) sred[wid] = s;
  __syncthreads();
  s = sred[0] + sred[1] + sred[2] + sred[3];
  float inv = 1.f / s;

  if (act) {
    ushortx8 o;
#pragma unroll
    for (int t = 0; t < 8; ++t) o[t] = f2bf(e[t] * inv);
    *(ushortx8*)(rp + cb) = o;
  }
}

extern "C" void kernel_launch(void* const* d_in, const int* in_sizes, int n_in,
                              void* d_out, int out_size, void* d_ws, size_t ws_size,
                              hipStream_t stream) {
  const float* queries = (const float*)d_in[0];    // [8,2048,1024]
  const float* keys = (const float*)d_in[1];       // [8,2048,1024]
  const float* values = (const float*)d_in[2];     // [8,2048,1024]
  const int* valid_lens = (const int*)d_in[3];     // [8]
  const float* W_q = (const float*)d_in[4];        // [1024,1024]
  float* out = (float*)d_out;                      // [8,2048,1024] fp32

  // Re-association: scores = Q @ (K @ W^T)^T — project KEYS (maskable), not queries.
  // ws layout (ushort elems), total 81M = 162 MiB:
  //   q_bf    [0, 16M)      queries bf16
  //   scores  [16M, 48M)
  //   keysP   [48M, 64M)    K@W^T bf16; dead after GEMM2 -> valsT aliases it
  //   w_bf    [64M, 65M)    W_q bf16 row-major (= B^T operand as-is)
  //   keys_bf [65M, 81M)
  unsigned short* ws = (unsigned short*)d_ws;
  const size_t M1 = (size_t)1024 * 1024;
  unsigned short* q_bf = ws;
  unsigned short* scores = ws + 16 * M1;
  unsigned short* keysP = ws + 48 * M1;
  unsigned short* valsT = keysP;  // alias — transpose runs after GEMM2
  unsigned short* w_bf = ws + 64 * M1;
  unsigned short* keys_bf = ws + 65 * M1;

  // casts: queries + keys(row-clamped to round256(vl)) + W_q
  cast3_bf16_kernel<<<dim3(16896), 256, 0, stream>>>(
      queries, q_bf, keys, keys_bf, W_q, w_bf, valid_lens);
  // GEMM1': keysP[b] = keys_bf[b] @ W_q^T -> bf16 [2048,1024]; skip m-tiles >= vl
  gemm256_kernel<0, 0, 1, 0><<<dim3(4, 8, 8), 512, 0, stream>>>(
      keys_bf, w_bf, keysP, 2048, 1024, 1024,
      (long)2048 * 1024, 0, (long)2048 * 1024, 1.f, valid_lens);
  // GEMM2': scores = q_bf @ keysP^T / 32 -> bf16 [8][2048][2048]; skip masked n-tiles
  gemm256_kernel<1, 1, 0, 0><<<dim3(8, 8, 8), 512, 0, stream>>>(
      q_bf, keysP, scores, 2048, 2048, 1024,
      (long)2048 * 1024, (long)2048 * 1024, (long)2048 * 2048, 0.03125f, valid_lens);
  // valsT[b][v][s] = values[b][s][v] (bf16), s-tiles clamped to round64(vl).
  transpose_cast_kernel<<<dim3(32, 64, 8), dim3(32, 8), 0, stream>>>(
      values, valsT, 2048, 1024, (long)2048 * 1024, (long)1024 * 2048, valid_lens);
  // softmax rows (masked by valid_lens), in place — writes exact 0 for cols>=vl
  softmax_kernel<<<dim3(B_ * LQ_), 256, 0, stream>>>(scores, valid_lens);
  // GEMM3: out = attn @ values (fp32 epilogue); K-loop clamped to valid_len
  gemm256_kernel<2, 0, 0, 1><<<dim3(4, 8, 8), 512, 0, stream>>>(
      scores, valsT, out, 2048, 1024, 2048,
      (long)2048 * 2048, (long)1024 * 2048, (long)2048 * 1024, 1.f, valid_lens);
}